// Round 1
// baseline (220.031 us; speedup 1.0000x reference)
//
#include <hip/hip_runtime.h>

// MFELoss: fused softmax(C=4) + masked-mean reduction to a scalar.
// R7: single-kernel fusion. mfe_final (1-block, 96KB gather, ~6-9us incl.
// launch slot) is replaced by a last-block-done ticket reduction inside the
// main kernel. A 4-byte hipMemsetAsync re-zeros the ticket every replay
// (workspace may be poisoned between iterations, so the counter cannot
// self-reset). Cross-XCD visibility: publish block partials with regular
// stores + __threadfence() (release), ticket via agent-scope ACQ_REL
// fetch_add, last block reads partials with agent-scope atomic loads.
// Result is deterministic: whichever block arrives last performs the same
// fixed-order reduction over 512x3 doubles.
// Load pipeline unchanged from R6 (proven):
//  - exact co-resident grid: 512 blocks x 1024 thr
//  - register double-buffer: prefetch chunk s+1 before computing chunk s
//  - non-temporal loads on both streams
// ~140-157 us of reported dur_us is fixed harness restore/poison overhead.

#define BLOCK 1024
#define ROWS 16
#define CHUNK 4
#define STAGES (ROWS / CHUNK)
#define WAVES (BLOCK / 64)

typedef float vfloat4 __attribute__((ext_vector_type(4)));

__device__ __forceinline__ void mfe_row(vfloat4 x, int t, int o,
                                        float& fne_acc, float& fpe_acc,
                                        float& cnt_acc) {
    float m = fmaxf(fmaxf(x.x, x.y), fmaxf(x.z, x.w));
    float e0 = __expf(x.x - m);
    float e1 = __expf(x.y - m);
    float e2 = __expf(x.z - m);
    float e3 = __expf(x.w - m);
    float S = (e0 + e1) + (e2 + e3);
    float r = 1.0f / S;
    float p0 = e0 * r, p1 = e1 * r, p2 = e2 * r, p3 = e3 * r;
    float s = ((p0 + p1) + p2) + p3;          // ~1.0, computed faithfully
    float po = (o == 0) ? p0 : (o == 1) ? p1 : (o == 2) ? p2 : p3;

    float d1 = s - po;
    float d2 = po - 1.0f;
    float fne_i = 0.5f * (d1 * d1 + d2 * d2);
    float fpe_i = po * po;                    // 0.5*(po^2+po^2)

    bool is_o = (t == o);
    fne_acc += is_o ? fne_i : 0.0f;
    fpe_acc += is_o ? 0.0f : fpe_i;
    cnt_acc += is_o ? 1.0f : 0.0f;            // exact in fp32 at these counts
}

__global__ __launch_bounds__(BLOCK) void mfe_fused(
    const vfloat4* __restrict__ preds,
    const int* __restrict__ target,
    const int* __restrict__ others_idx_p,
    double* __restrict__ fne_b,
    double* __restrict__ fpe_b,
    double* __restrict__ cnt_b,
    unsigned* __restrict__ ticket,
    int n_rows,
    float* __restrict__ out)
{
    const int o = *others_idx_p;  // wave-uniform scalar
    int tid = blockIdx.x * BLOCK + threadIdx.x;
    int nth = gridDim.x * BLOCK;

    float fne_acc = 0.0f, fpe_acc = 0.0f, cnt_acc = 0.0f;

    if (tid + (ROWS - 1) * nth < n_rows) {
        vfloat4 xbuf[2][CHUNK];
        int     tbuf[2][CHUNK];

        // prologue: fill buffer 0
        #pragma unroll
        for (int k = 0; k < CHUNK; ++k) {
            int i = tid + k * nth;
            xbuf[0][k] = __builtin_nontemporal_load(&preds[i]);
            tbuf[0][k] = __builtin_nontemporal_load(&target[i]);
        }

        #pragma unroll
        for (int s = 0; s < STAGES; ++s) {
            int cur = s & 1;
            int nxt = cur ^ 1;
            // prefetch next chunk before touching current one
            if (s + 1 < STAGES) {
                #pragma unroll
                for (int k = 0; k < CHUNK; ++k) {
                    int i = tid + ((s + 1) * CHUNK + k) * nth;
                    xbuf[nxt][k] = __builtin_nontemporal_load(&preds[i]);
                    tbuf[nxt][k] = __builtin_nontemporal_load(&target[i]);
                }
            }
            // pin prefetch issue before compute
            __builtin_amdgcn_sched_barrier(0);
            #pragma unroll
            for (int k = 0; k < CHUNK; ++k)
                mfe_row(xbuf[cur][k], tbuf[cur][k], o, fne_acc, fpe_acc, cnt_acc);
        }
    } else {
        for (int i = tid; i < n_rows; i += nth)
            mfe_row(preds[i], target[i], o, fne_acc, fpe_acc, cnt_acc);
    }

    // 64-lane wave reduction (fp32, identical to R6)
    #pragma unroll
    for (int off = 32; off > 0; off >>= 1) {
        fne_acc += __shfl_down(fne_acc, off, 64);
        fpe_acc += __shfl_down(fpe_acc, off, 64);
        cnt_acc += __shfl_down(cnt_acc, off, 64);
    }

    // block reduction in double (accuracy >= old per-wave fp32 partial path)
    __shared__ double s_fn[WAVES], s_fp[WAVES], s_c[WAVES];
    __shared__ int s_last;
    int wave = threadIdx.x >> 6;
    int lane = threadIdx.x & 63;
    if (lane == 0) {
        s_fn[wave] = (double)fne_acc;
        s_fp[wave] = (double)fpe_acc;
        s_c[wave]  = (double)cnt_acc;
    }
    __syncthreads();

    if (threadIdx.x == 0) {
        double fn = 0.0, fp = 0.0, c = 0.0;
        #pragma unroll
        for (int w = 0; w < WAVES; ++w) { fn += s_fn[w]; fp += s_fp[w]; c += s_c[w]; }
        // publish block partial (release: fence before ticket bump)
        fne_b[blockIdx.x] = fn;
        fpe_b[blockIdx.x] = fp;
        cnt_b[blockIdx.x] = c;
        __threadfence();
        unsigned t = __hip_atomic_fetch_add(ticket, 1u, __ATOMIC_ACQ_REL,
                                            __HIP_MEMORY_SCOPE_AGENT);
        s_last = (t == gridDim.x - 1) ? 1 : 0;
    }
    __syncthreads();
    if (!s_last) return;

    // ---- last-arriving block: final reduction over all block partials ----
    // Fixed index order -> deterministic regardless of which block runs it.
    double fn = 0.0, fp = 0.0, c = 0.0;
    for (int i = threadIdx.x; i < (int)gridDim.x; i += BLOCK) {
        fn += __hip_atomic_load(&fne_b[i], __ATOMIC_RELAXED, __HIP_MEMORY_SCOPE_AGENT);
        fp += __hip_atomic_load(&fpe_b[i], __ATOMIC_RELAXED, __HIP_MEMORY_SCOPE_AGENT);
        c  += __hip_atomic_load(&cnt_b[i], __ATOMIC_RELAXED, __HIP_MEMORY_SCOPE_AGENT);
    }
    #pragma unroll
    for (int off = 32; off > 0; off >>= 1) {
        fn += __shfl_down(fn, off, 64);
        fp += __shfl_down(fp, off, 64);
        c  += __shfl_down(c, off, 64);
    }
    __syncthreads();   // s_fn/s_fp/s_c reuse
    if (lane == 0) { s_fn[wave] = fn; s_fp[wave] = fp; s_c[wave] = c; }
    __syncthreads();

    if (threadIdx.x == 0) {
        double tfn = 0.0, tfp = 0.0, tc = 0.0;
        #pragma unroll
        for (int w = 0; w < WAVES; ++w) { tfn += s_fn[w]; tfp += s_fp[w]; tc += s_c[w]; }
        double fne_num = tc;
        double fpe_num = (double)n_rows - tc;
        double res = 0.0;
        if (fpe_num > 0.0) res += tfp / fpe_num;
        if (fne_num > 0.0) res += tfn / fne_num;
        out[0] = (float)res;
    }
}

extern "C" void kernel_launch(void* const* d_in, const int* in_sizes, int n_in,
                              void* d_out, int out_size, void* d_ws, size_t ws_size,
                              hipStream_t stream) {
    const vfloat4* preds = (const vfloat4*)d_in[0];
    const int* target = (const int*)d_in[1];
    const int* others_idx = (const int*)d_in[2];
    float* out = (float*)d_out;

    int n_rows = in_sizes[0] / 4;   // B = 8388608

    int grid = (n_rows + BLOCK * ROWS - 1) / (BLOCK * ROWS);  // 512 for B=2^23

    double* fne_b = (double*)d_ws;
    double* fpe_b = fne_b + grid;
    double* cnt_b = fpe_b + grid;
    unsigned* ticket = (unsigned*)(cnt_b + grid);

    // workspace may be poisoned between replays: ticket must start at 0
    hipMemsetAsync(ticket, 0, sizeof(unsigned), stream);

    mfe_fused<<<grid, BLOCK, 0, stream>>>(preds, target, others_idx,
                                          fne_b, fpe_b, cnt_b, ticket,
                                          n_rows, out);
}

// Round 2
// 201.218 us; speedup vs baseline: 1.0935x; 1.0935x over previous
//
#include <hip/hip_runtime.h>

// MFELoss: fused softmax(C=4) + masked-mean reduction to a scalar.
// R8 = R6 revert + smaller handoff. R7's single-kernel ticket fusion
// REGRESSED +17us: 512 blocks each paid __threadfence + agent-scope atomic
// (L2 writeback on non-coherent-XCD gfx950). The kernel boundary is the
// cheapest device-scope fence -- keep two kernels.
// Change vs R6: block-level double partials (512x3, 12KB) instead of
// per-wave fp32 partials (8192x3, 96KB). One LDS+syncthreads tail in the
// main kernel (hidden under kernel drain); final kernel gather 96KB->12KB.
// Load pipeline byte-identical to R6 (proven 202.9us):
//  - exact co-resident grid: 512 blocks x 1024 thr
//  - register double-buffer: prefetch chunk s+1 before computing chunk s
//  - non-temporal loads on both streams
// ~157 us of reported dur_us is fixed harness poison-fill overhead (2x78us).

#define BLOCK 1024
#define ROWS 16
#define CHUNK 4
#define STAGES (ROWS / CHUNK)
#define WAVES (BLOCK / 64)

typedef float vfloat4 __attribute__((ext_vector_type(4)));

__device__ __forceinline__ void mfe_row(vfloat4 x, int t, int o,
                                        float& fne_acc, float& fpe_acc,
                                        float& cnt_acc) {
    float m = fmaxf(fmaxf(x.x, x.y), fmaxf(x.z, x.w));
    float e0 = __expf(x.x - m);
    float e1 = __expf(x.y - m);
    float e2 = __expf(x.z - m);
    float e3 = __expf(x.w - m);
    float S = (e0 + e1) + (e2 + e3);
    float r = 1.0f / S;
    float p0 = e0 * r, p1 = e1 * r, p2 = e2 * r, p3 = e3 * r;
    float s = ((p0 + p1) + p2) + p3;          // ~1.0, computed faithfully
    float po = (o == 0) ? p0 : (o == 1) ? p1 : (o == 2) ? p2 : p3;

    float d1 = s - po;
    float d2 = po - 1.0f;
    float fne_i = 0.5f * (d1 * d1 + d2 * d2);
    float fpe_i = po * po;                    // 0.5*(po^2+po^2)

    bool is_o = (t == o);
    fne_acc += is_o ? fne_i : 0.0f;
    fpe_acc += is_o ? 0.0f : fpe_i;
    cnt_acc += is_o ? 1.0f : 0.0f;            // exact in fp32 at these counts
}

__global__ __launch_bounds__(BLOCK) void mfe_partial(
    const vfloat4* __restrict__ preds,
    const int* __restrict__ target,
    const int* __restrict__ others_idx_p,
    double* __restrict__ fne_b,
    double* __restrict__ fpe_b,
    double* __restrict__ cnt_b,
    int n_rows)
{
    const int o = *others_idx_p;  // wave-uniform scalar
    int tid = blockIdx.x * BLOCK + threadIdx.x;
    int nth = gridDim.x * BLOCK;

    float fne_acc = 0.0f, fpe_acc = 0.0f, cnt_acc = 0.0f;

    if (tid + (ROWS - 1) * nth < n_rows) {
        vfloat4 xbuf[2][CHUNK];
        int     tbuf[2][CHUNK];

        // prologue: fill buffer 0
        #pragma unroll
        for (int k = 0; k < CHUNK; ++k) {
            int i = tid + k * nth;
            xbuf[0][k] = __builtin_nontemporal_load(&preds[i]);
            tbuf[0][k] = __builtin_nontemporal_load(&target[i]);
        }

        #pragma unroll
        for (int s = 0; s < STAGES; ++s) {
            int cur = s & 1;
            int nxt = cur ^ 1;
            // prefetch next chunk before touching current one
            if (s + 1 < STAGES) {
                #pragma unroll
                for (int k = 0; k < CHUNK; ++k) {
                    int i = tid + ((s + 1) * CHUNK + k) * nth;
                    xbuf[nxt][k] = __builtin_nontemporal_load(&preds[i]);
                    tbuf[nxt][k] = __builtin_nontemporal_load(&target[i]);
                }
            }
            // pin prefetch issue before compute
            __builtin_amdgcn_sched_barrier(0);
            #pragma unroll
            for (int k = 0; k < CHUNK; ++k)
                mfe_row(xbuf[cur][k], tbuf[cur][k], o, fne_acc, fpe_acc, cnt_acc);
        }
    } else {
        for (int i = tid; i < n_rows; i += nth)
            mfe_row(preds[i], target[i], o, fne_acc, fpe_acc, cnt_acc);
    }

    // 64-lane wave reduction (fp32, identical to R6)
    #pragma unroll
    for (int off = 32; off > 0; off >>= 1) {
        fne_acc += __shfl_down(fne_acc, off, 64);
        fpe_acc += __shfl_down(fpe_acc, off, 64);
        cnt_acc += __shfl_down(cnt_acc, off, 64);
    }

    // block reduction in double -> one partial triple per block (12KB total)
    __shared__ double s_fn[WAVES], s_fp[WAVES], s_c[WAVES];
    int wave = threadIdx.x >> 6;
    int lane = threadIdx.x & 63;
    if (lane == 0) {
        s_fn[wave] = (double)fne_acc;
        s_fp[wave] = (double)fpe_acc;
        s_c[wave]  = (double)cnt_acc;
    }
    __syncthreads();
    if (threadIdx.x == 0) {
        double fn = 0.0, fp = 0.0, c = 0.0;
        #pragma unroll
        for (int w = 0; w < WAVES; ++w) { fn += s_fn[w]; fp += s_fp[w]; c += s_c[w]; }
        fne_b[blockIdx.x] = fn;
        fpe_b[blockIdx.x] = fp;
        cnt_b[blockIdx.x] = c;
        // visibility to mfe_final: implicit end-of-kernel release + stream order
    }
}

__global__ __launch_bounds__(512) void mfe_final(
    const double* __restrict__ fne_b,
    const double* __restrict__ fpe_b,
    const double* __restrict__ cnt_b,
    int nblocks, int n_rows, float* __restrict__ out)
{
    double fn = 0.0, fp = 0.0, c = 0.0;
    for (int i = threadIdx.x; i < nblocks; i += 512) {
        fn += fne_b[i];
        fp += fpe_b[i];
        c  += cnt_b[i];
    }
    #pragma unroll
    for (int off = 32; off > 0; off >>= 1) {
        fn += __shfl_down(fn, off, 64);
        fp += __shfl_down(fp, off, 64);
        c  += __shfl_down(c, off, 64);
    }
    __shared__ double s_fn[8], s_fp[8], s_c[8];
    int wave = threadIdx.x >> 6;
    int lane = threadIdx.x & 63;
    if (lane == 0) { s_fn[wave] = fn; s_fp[wave] = fp; s_c[wave] = c; }
    __syncthreads();

    if (threadIdx.x == 0) {
        double tfn = 0.0, tfp = 0.0, tc = 0.0;
        #pragma unroll
        for (int w = 0; w < 8; ++w) { tfn += s_fn[w]; tfp += s_fp[w]; tc += s_c[w]; }
        double fne_num = tc;
        double fpe_num = (double)n_rows - tc;
        double res = 0.0;
        if (fpe_num > 0.0) res += tfp / fpe_num;
        if (fne_num > 0.0) res += tfn / fne_num;
        out[0] = (float)res;
    }
}

extern "C" void kernel_launch(void* const* d_in, const int* in_sizes, int n_in,
                              void* d_out, int out_size, void* d_ws, size_t ws_size,
                              hipStream_t stream) {
    const vfloat4* preds = (const vfloat4*)d_in[0];
    const int* target = (const int*)d_in[1];
    const int* others_idx = (const int*)d_in[2];
    float* out = (float*)d_out;

    int n_rows = in_sizes[0] / 4;   // B = 8388608

    int grid = (n_rows + BLOCK * ROWS - 1) / (BLOCK * ROWS);  // 512 for B=2^23

    double* fne_b = (double*)d_ws;
    double* fpe_b = fne_b + grid;
    double* cnt_b = fpe_b + grid;

    mfe_partial<<<grid, BLOCK, 0, stream>>>(preds, target, others_idx,
                                            fne_b, fpe_b, cnt_b, n_rows);
    mfe_final<<<1, 512, 0, stream>>>(fne_b, fpe_b, cnt_b, grid, n_rows, out);
}